// Round 3
// baseline (214.026 us; speedup 1.0000x reference)
//
#include <hip/hip_runtime.h>
#include <hip/hip_bf16.h>

// Problem constants: B=64, S=512, H=768, L=9
#define NB 64
#define NS 512
#define NH 768
#define NL 9
#define NROWS (NB*NS)          // 32768
#define EMN (NROWS*NL)         // 294912

// per-batch LDS strides (padded off %32==0 to avoid 4-way batch bank aliasing)
#define VST  4617              // floats per batch for s_v   (>= 512*9=4608)
#define BPST 4616              // bytes  per batch for s_bp  (>= 4608)

__device__ __forceinline__ float readlane_f(float v, int l) {
    return __int_as_float(__builtin_amdgcn_readlane(__float_as_int(v), l));
}
__device__ __forceinline__ unsigned long long readlane_u64(unsigned long long v, int l) {
    unsigned int lo = (unsigned int)__builtin_amdgcn_readlane((int)(unsigned int)(v & 0xffffffffULL), l);
    unsigned int hi = (unsigned int)__builtin_amdgcn_readlane((int)(unsigned int)(v >> 32), l);
    return ((unsigned long long)hi << 32) | (unsigned long long)lo;
}
// DPP add: x += dpp_move(x, CTRL); out-of-bound source lanes contribute 0.
template <int CTRL>
__device__ __forceinline__ float dpp_add(float x) {
    int t = __builtin_amdgcn_update_dpp(0, __float_as_int(x), CTRL, 0xf, 0xf, false);
    return x + __int_as_float(t);
}
// Canonical gfx9 wave64 sum; total lands in lane 63. Pure VALU (no LDS pipe).
__device__ __forceinline__ float wave_sum_to63(float x) {
    x = dpp_add<0x111>(x);  // row_shr:1
    x = dpp_add<0x112>(x);  // row_shr:2
    x = dpp_add<0x114>(x);  // row_shr:4
    x = dpp_add<0x118>(x);  // row_shr:8  (lane15 of each row = row sum)
    x = dpp_add<0x142>(x);  // row_bcast:15
    x = dpp_add<0x143>(x);  // row_bcast:31 -> lane63 = wave sum
    return x;
}
// ds_swizzle row-broadcast: every lane receives the value held by lane
// (lane & 0x10) | I of its 32-lane group == lane I of its own 16-lane row.
// BitMode offset = (xor<<10) | (or<<5) | and  ->  (I<<5) | 0x10.
template <int I>
__device__ __forceinline__ float rowbc(float x) {
    return __int_as_float(__builtin_amdgcn_ds_swizzle(__float_as_int(x), (I << 5) | 0x10));
}

// ---------------- Kernel A: emissions GEMM v2 ----------------
// 2048 blocks x 192 thr (3 waves). Block handles rows 16bx..16bx+15.
// Wave w owns k-chunk [256w, 256w+256); lane l owns k = 256w+4l..+3 (float4).
// hidden: ONE aligned float4 load per row per thread (1KB per wave-instr, all
// 64 lanes active) vs the old 3 scalar dwords (256B/instr) -> 4x fewer load
// instrs at full coalescing. W: 9 aligned float4 loads = 36 floats/lane
// (4k x 9j), amortized over 16 rows (W re-traffic 226MB -> 56MB of L2).
// Reduction: proven wave_sum_to63 tree + 3-wave LDS combine.
__global__ __launch_bounds__(192) void k_gemm(const float* __restrict__ hidden,
                                              const float* __restrict__ W,
                                              const float* __restrict__ bias,
                                              float* __restrict__ em,
                                              float* __restrict__ out) {
    __shared__ float s_part[3][16][NL];   // [wave][row][j] = 1.7KB
    int tid = threadIdx.x;
    int lane = tid & 63;
    int w = tid >> 6;                     // 0..2
    int bx = blockIdx.x;
    if (bx == 0 && tid == 0) { out[0] = 0.f; out[1] = 0.f; }

    int kbase = 256 * w + 4 * lane;       // this lane's 4 consecutive k
    // W preload: 36 consecutive floats = 9 aligned float4s (base = kbase*36B,
    // 16B-divisible since 144 | lane stride and 9216 | wave stride).
    float4 wq[9];
    const float4* wp4 = (const float4*)(W + (size_t)kbase * NL);
#pragma unroll
    for (int i = 0; i < 9; i++) wq[i] = wp4[i];
    float Wv[4][NL];
#pragma unroll
    for (int a = 0; a < 4; a++) {
#pragma unroll
        for (int j = 0; j < NL; j++) {
            Wv[a][j] = ((const float*)wq)[a * NL + j];
        }
    }

#pragma unroll 4
    for (int r = 0; r < 16; r++) {
        int row = 16 * bx + r;
        const float4 h = *(const float4*)(hidden + (size_t)row * NH + kbase);
        float acc[NL];
#pragma unroll
        for (int j = 0; j < NL; j++) {
            acc[j] = fmaf(h.x, Wv[0][j],
                     fmaf(h.y, Wv[1][j],
                     fmaf(h.z, Wv[2][j], h.w * Wv[3][j])));
        }
#pragma unroll
        for (int j = 0; j < NL; j++) acc[j] = wave_sum_to63(acc[j]);
        if (lane == 63) {
#pragma unroll
            for (int j = 0; j < NL; j++) s_part[w][r][j] = acc[j];
        }
    }
    __syncthreads();
    if (tid < 144) {
        int r = tid / NL, j = tid % NL;
        float v = (s_part[0][r][j] + s_part[1][r][j]) + s_part[2][r][j] + bias[j];
        em[(size_t)(16 * bx + r) * NL + j] = v;
    }
}

// ---------------- Kernel B: DP + finalize (4 batches per wave via row-broadcast) ----
// (round-2 proven version, unchanged: 44.6us)
// blocks [0,16):  wave0 = forward chains for batches 4bx..4bx+3 (one 16-lane row each)
//                 wave1 = gold-path numerator, one 16-lane group per batch
// blocks [16,32): wave0 = 4 Viterbi value chains; then phases 2/3/finalize block-wide
__global__ __launch_bounds__(256) void k_dp(const float* __restrict__ em,
                                            const int* __restrict__ label,
                                            const int* __restrict__ mask,
                                            const float* __restrict__ startT,
                                            const float* __restrict__ endT,
                                            const float* __restrict__ trans,
                                            float* __restrict__ out) {
    __shared__ float s_T[NL * NL];
    __shared__ int s_mki[4][NS];                 // masks for the block's 4 batches
    __shared__ float s_v[4 * VST];               // viterbi value history (padded stride)
    __shared__ unsigned char s_bp[4 * BPST];     // backpointers
    __shared__ unsigned char s_path[4 * NS];     // decoded paths

    int bx = blockIdx.x;
    int tid = threadIdx.x;
    int lane = tid & 63;
    bool isfwd = bx < 16;
    int b0 = (isfwd ? bx : (bx - 16)) * 4;

    if (tid < NL * NL) s_T[tid] = trans[tid];
    if (isfwd) {
        for (int q = tid; q < 4 * NS / 4; q += 256)
            ((int4*)s_mki)[q] = ((const int4*)(mask + b0 * NS))[q];
    }
    __syncthreads();

    if (isfwd) {
        if (tid < 64) {
            // ---- forward algorithm, 4 batches (one per 16-lane row) ----
            int bb = lane >> 4;
            int jcol = lane & 15;
            int jcol9 = jcol < NL ? jcol : NL - 1;
            const float* gp = em + (size_t)(b0 + bb) * (NS * NL) + jcol9;
            float Mc0 = __expf(s_T[0 * NL + jcol9]);
            float Mc1 = __expf(s_T[1 * NL + jcol9]);
            float Mc2 = __expf(s_T[2 * NL + jcol9]);
            float Mc3 = __expf(s_T[3 * NL + jcol9]);
            float Mc4 = __expf(s_T[4 * NL + jcol9]);
            float Mc5 = __expf(s_T[5 * NL + jcol9]);
            float Mc6 = __expf(s_T[6 * NL + jcol9]);
            float Mc7 = __expf(s_T[7 * NL + jcol9]);
            float Mc8 = __expf(s_T[8 * NL + jcol9]);
            float a = __expf(startT[jcol9] + gp[0]);
            int eacc = 0;

#define FBODY(EC_, KC_) do { \
    float _w0=rowbc<0>(a),_w1=rowbc<1>(a),_w2=rowbc<2>(a),_w3=rowbc<3>(a),_w4=rowbc<4>(a), \
          _w5=rowbc<5>(a),_w6=rowbc<6>(a),_w7=rowbc<7>(a),_w8=rowbc<8>(a); \
    float _p0=_w0*Mc0,_p1=_w1*Mc1,_p2=_w2*Mc2,_p3=_w3*Mc3,_p4=_w4*Mc4, \
          _p5=_w5*Mc5,_p6=_w6*Mc6,_p7=_w7*Mc7,_p8=_w8*Mc8; \
    float _s=(((_p0+_p1)+(_p2+_p3))+((_p4+_p5)+(_p6+_p7)))+_p8; \
    float _an=(EC_)*_s; \
    a = ((KC_) > 0) ? _an : a; \
} while (0)

#define FREN() do { \
    float _c0=rowbc<0>(a),_c1=rowbc<1>(a),_c2=rowbc<2>(a),_c3=rowbc<3>(a),_c4=rowbc<4>(a), \
          _c5=rowbc<5>(a),_c6=rowbc<6>(a),_c7=rowbc<7>(a),_c8=rowbc<8>(a); \
    float _cc=(((_c0+_c1)+(_c2+_c3))+((_c4+_c5)+(_c6+_c7)))+_c8; \
    int _ex=((__float_as_int(_cc)>>23)&255)-127; \
    a=ldexpf(a,-_ex); eacc+=_ex; \
} while (0)

            float e8[8]; int k8[8];
#pragma unroll
            for (int p = 0; p < 8; p++) {
                e8[p] = __expf(gp[(1 + p) * NL]);
                k8[p] = s_mki[bb][1 + p];
            }
            for (int t0 = 1; t0 <= NS - 15; t0 += 8) {   // t0 = 1,9,...,497
#pragma unroll
                for (int p = 0; p < 8; p++) {
                    int t = t0 + p;
                    float ec = e8[p]; int kc = k8[p];
                    int tn = t + 8; tn = tn > NS - 1 ? NS - 1 : tn;
                    e8[p] = __expf(gp[tn * NL]);         // prefetch 8 ahead
                    k8[p] = s_mki[bb][tn];
                    FBODY(ec, kc);
                    if (p == 7) FREN();                  // t = 8,16,...,504
                }
            }
#pragma unroll
            for (int p = 0; p < 7; p++) FBODY(e8[p], k8[p]);   // t = 505..511
#undef FBODY
#undef FREN
            float z = a * __expf(endT[jcol9]);
            float c0 = rowbc<0>(z), c1 = rowbc<1>(z), c2 = rowbc<2>(z);
            float c3 = rowbc<3>(z), c4 = rowbc<4>(z), c5 = rowbc<5>(z);
            float c6 = rowbc<6>(z), c7 = rowbc<7>(z), c8 = rowbc<8>(z);
            float c = (((c0 + c1) + (c2 + c3)) + ((c4 + c5) + (c6 + c7))) + c8;
            if (jcol == 0) {
                float lz = (float)eacc * 0.6931471805599453f + __logf(c);
                atomicAdd(out, lz * (1.0f / (float)NB));
            }
        } else if (tid < 128) {
            // ---- numerator (gold path score), one 16-lane group per batch ----
            int g = lane >> 4;
            int ll = lane & 15;
            int b = b0 + g;
            const int* lb = label + b * NS;
            const float* ge = em + (size_t)b * NS * NL;
            int h = 0, sl = 0;
            for (int cch = 0; cch < 4; cch++) {
                int la8[8]; int mk8[8];
#pragma unroll
                for (int r = 0; r < 8; r++) {
                    int t = ll * 32 + cch * 8 + r;
                    la8[r] = lb[t];
                    int m = s_mki[g][t];
                    if (t == 0) m = 1;
                    mk8[r] = m;
                }
#pragma unroll
                for (int r = 0; r < 8; r++) if (mk8[r] > 0) { h = 1; sl = la8[r]; }
            }
#pragma unroll
            for (int d = 1; d < 16; d <<= 1) {
                int ho = __shfl_up(h, d, 16);
                int so = __shfl_up(sl, d, 16);
                if (!h) { h = ho; sl = so; }
            }
            int lg = __shfl(sl, 15, 16);
            int incoming = __shfl_up(sl, 1, 16);
            int labz = lb[0];
            int prevr = (ll == 0) ? labz : incoming;
            float sc = 0.f;
            for (int cch = 0; cch < 4; cch++) {
                int la8[8]; int mk8[8]; float ev8[8];
#pragma unroll
                for (int r = 0; r < 8; r++) {
                    int t = ll * 32 + cch * 8 + r;
                    la8[r] = lb[t];
                    int m = s_mki[g][t];
                    if (t == 0) m = 1;
                    mk8[r] = m;
                }
#pragma unroll
                for (int r = 0; r < 8; r++) {
                    int t = ll * 32 + cch * 8 + r;
                    ev8[r] = ge[t * NL + la8[r]];
                }
#pragma unroll
                for (int r = 0; r < 8; r++) {
                    int t = ll * 32 + cch * 8 + r;
                    if (t > 0) {
                        float s = s_T[prevr * NL + la8[r]] + ev8[r];
                        sc += s * (float)mk8[r];
                    }
                    if (mk8[r] > 0) prevr = la8[r];
                }
            }
            if (ll == 0) sc += startT[labz] + ge[labz] + endT[lg];
#pragma unroll
            for (int d = 1; d < 16; d <<= 1) sc += __shfl_xor(sc, d, 16);
            if (ll == 0) atomicAdd(out, -sc * (1.0f / (float)NB));
        }
    } else {
        // ---- Viterbi phase 1: 4 value chains (one per 16-lane row), bit-exact ----
        if (tid < 64) {
            int bb = lane >> 4;
            int jcol = lane & 15;
            int jcol9 = jcol < NL ? jcol : NL - 1;
            const float* gv = em + (size_t)(b0 + bb) * (NS * NL) + jcol9;
            float Tc0 = s_T[0 * NL + jcol9];
            float Tc1 = s_T[1 * NL + jcol9];
            float Tc2 = s_T[2 * NL + jcol9];
            float Tc3 = s_T[3 * NL + jcol9];
            float Tc4 = s_T[4 * NL + jcol9];
            float Tc5 = s_T[5 * NL + jcol9];
            float Tc6 = s_T[6 * NL + jcol9];
            float Tc7 = s_T[7 * NL + jcol9];
            float Tc8 = s_T[8 * NL + jcol9];
            float v = startT[jcol9] + gv[0];
            int svbase = bb * VST + jcol;
            s_v[svbase] = v;   // t = 0

#define VBODY(EC_, T_) do { \
    float _w0=rowbc<0>(v),_w1=rowbc<1>(v),_w2=rowbc<2>(v),_w3=rowbc<3>(v),_w4=rowbc<4>(v), \
          _w5=rowbc<5>(v),_w6=rowbc<6>(v),_w7=rowbc<7>(v),_w8=rowbc<8>(v); \
    float _m0=_w0+Tc0,_m1=_w1+Tc1,_m2=_w2+Tc2,_m3=_w3+Tc3,_m4=_w4+Tc4, \
          _m5=_w5+Tc5,_m6=_w6+Tc6,_m7=_w7+Tc7,_m8=_w8+Tc8; \
    float _Ma=fmaxf(fmaxf(_m0,_m1),_m2); \
    float _Mb=fmaxf(fmaxf(_m3,_m4),_m5); \
    float _Mc=fmaxf(fmaxf(_m6,_m7),_m8); \
    v = fmaxf(fmaxf(_Ma,_Mb),_Mc) + (EC_); \
    s_v[svbase + (T_) * NL] = v; \
} while (0)

            float e8[8];
#pragma unroll
            for (int p = 0; p < 8; p++) e8[p] = gv[(1 + p) * NL];
            for (int t0 = 1; t0 <= NS - 15; t0 += 8) {
#pragma unroll
                for (int p = 0; p < 8; p++) {
                    int t = t0 + p;
                    float ec = e8[p];
                    int tn = t + 8; tn = tn > NS - 1 ? NS - 1 : tn;
                    e8[p] = gv[tn * NL];
                    VBODY(ec, t);
                }
            }
#pragma unroll
            for (int p = 0; p < 7; p++) VBODY(e8[p], 505 + p);
#undef VBODY
        }
        __syncthreads();
        // ---- phase 2: backpointers, parallel over (batch, t); exact ref op order ----
        for (int it = 0; it < 8; it++) {
            int item = tid + it * 256;
            int bb = item >> 9;
            int t = item & (NS - 1);
            if (t > 0) {
                const float* vpp = s_v + bb * VST + (t - 1) * NL;
                const float* ge = em + (size_t)(b0 + bb) * (NS * NL) + t * NL;
                float vp[NL], emt[NL];
#pragma unroll
                for (int i = 0; i < NL; i++) vp[i] = vpp[i];
#pragma unroll
                for (int j = 0; j < NL; j++) emt[j] = ge[j];
#pragma unroll
                for (int j = 0; j < NL; j++) {
                    float e = emt[j];
                    float val[NL];
#pragma unroll
                    for (int i = 0; i < NL; i++) val[i] = (vp[i] + s_T[i * NL + j]) + e;
                    bool c01 = val[0] >= val[1]; float m01 = c01 ? val[0] : val[1]; int i01 = c01 ? 0 : 1;
                    bool c23 = val[2] >= val[3]; float m23 = c23 ? val[2] : val[3]; int i23 = c23 ? 2 : 3;
                    bool c45 = val[4] >= val[5]; float m45 = c45 ? val[4] : val[5]; int i45 = c45 ? 4 : 5;
                    bool c67 = val[6] >= val[7]; float m67 = c67 ? val[6] : val[7]; int i67 = c67 ? 6 : 7;
                    bool ca = m01 >= m23; float ma = ca ? m01 : m23; int ia = ca ? i01 : i23;
                    bool cb = m45 >= m67; float mb = cb ? m45 : m67; int ib = cb ? i45 : i67;
                    bool cc = ma >= mb;  float mc = cc ? ma : mb;  int ic = cc ? ia : ib;
                    bool cd = mc >= val[8]; int bi = cd ? ic : 8;
                    s_bp[bb * BPST + t * NL + j] = (unsigned char)bi;
                }
            }
        }
        __syncthreads();
        // ---- phase 3: last tag + map-composition backtrack (wave w -> batch w) ----
        {
            int w = tid >> 6;
            const float* sv = s_v + w * VST;
            const unsigned char* bpp = s_bp + w * BPST;
            unsigned char* pth = s_path + w * NS;
            float bb2 = sv[(NS - 1) * NL + 0] + endT[0]; int lt = 0;
#pragma unroll
            for (int jj = 1; jj < NL; jj++) {
                float fj = sv[(NS - 1) * NL + jj] + endT[jj];
                if (fj > bb2) { bb2 = fj; lt = jj; }
            }
            unsigned long long G[8];
#pragma unroll
            for (int r = 0; r < 8; r++) {
                int t0 = (lane * 8 + r) * NL;
                unsigned long long g = 0;
                if (lane == 0 && r == 0) {
                    g = 0x876543210ULL;   // t=0 identity (bp[0] unused)
                } else {
#pragma unroll
                    for (int x = 0; x < NL; x++) g |= (unsigned long long)bpp[t0 + x] << (4 * x);
                }
                G[r] = g;
            }
            unsigned long long A = 0x876543210ULL;
#pragma unroll
            for (int r = 7; r >= 0; r--) {
                unsigned long long An = 0;
#pragma unroll
                for (int x = 0; x < NL; x++) {
                    int ax = (int)((A >> (4 * x)) & 15ULL);
                    int gvv = (int)((G[r] >> (4 * ax)) & 15ULL);
                    An |= (unsigned long long)gvv << (4 * x);
                }
                A = An;
            }
            int e = 0; int cur = lt;
            for (int llv = 63; llv >= 0; --llv) {
                if (lane == llv) e = cur;
                unsigned long long Al = readlane_u64(A, llv);
                cur = (int)((Al >> (4 * cur)) & 15ULL);
            }
            unsigned long long pw = 0; int c2 = e;
#pragma unroll
            for (int r = 7; r >= 0; r--) {
                pw |= (unsigned long long)c2 << (8 * r);
                c2 = (int)((G[r] >> (4 * c2)) & 15ULL);
            }
            *(unsigned long long*)(pth + lane * 8) = pw;
        }
        __syncthreads();
        // ---- finalize: predict/label/correct for the block's 4 batches ----
        float cnt = 0.f;
#pragma unroll
        for (int q = 0; q < 8; q++) {
            int item = tid + q * 256;
            int bb = item >> 9;
            int t = item & (NS - 1);
            int b = b0 + bb;
            int idx = b * NS + t;
            int lab = label[idx];
            int p = (int)s_path[bb * NS + t];
            int pred = (lab > 0) ? p : 0;
            out[2 + idx] = (float)pred;
            out[2 + NROWS + idx] = (float)lab;
            cnt += (pred == lab) ? 1.f : 0.f;
        }
#pragma unroll
        for (int d = 1; d < 64; d <<= 1) cnt += __shfl_xor(cnt, d);
        if ((tid & 63) == 0) atomicAdd(out + 1, cnt);
    }
}

extern "C" void kernel_launch(void* const* d_in, const int* in_sizes, int n_in,
                              void* d_out, int out_size, void* d_ws, size_t ws_size,
                              hipStream_t stream) {
    const float* hidden = (const float*)d_in[0];
    const int*   label  = (const int*)d_in[1];
    const int*   mask   = (const int*)d_in[2];
    const float* W      = (const float*)d_in[3];
    const float* bias   = (const float*)d_in[4];
    const float* startT = (const float*)d_in[5];
    const float* endT   = (const float*)d_in[6];
    const float* trans  = (const float*)d_in[7];
    float* out = (float*)d_out;

    float* em = (float*)d_ws;   // EMN floats

    k_gemm<<<2048, 192, 0, stream>>>(hidden, W, bias, em, out);
    k_dp<<<32, 256, 0, stream>>>(em, label, mask, startT, endT, trans, out);
}